// Round 2
// baseline (131.729 us; speedup 1.0000x reference)
//
#include <hip/hip_runtime.h>
#include <math.h>

#define NBATCH 8192
#define NNEI 256
#define NROLE 3
#define NHID 32
#define NDIM 6

// Pre-pack weights: pack[(r*32+h)*8 + {0..5,6,7}] = {W1[r][0..5][h], b1[r][h], W2[r][h]}
__global__ void hmf_prep(const float* __restrict__ W1,
                         const float* __restrict__ b1,
                         const float* __restrict__ W2,
                         float* __restrict__ pack) {
  int j = threadIdx.x;
  if (j < NROLE * NHID) {
    int r = j >> 5;
    int h = j & 31;
#pragma unroll
    for (int d = 0; d < NDIM; ++d)
      pack[j * 8 + d] = W1[(r * NDIM + d) * NHID + h];
    pack[j * 8 + 6] = b1[r * NHID + h];
    pack[j * 8 + 7] = W2[r * NHID + h];
  }
}

__global__ __launch_bounds__(256) void hmf_main(
    const float* __restrict__ states,
    const int* __restrict__ roles,
    const int* __restrict__ maskp,   // bool arrives as int32
    const float* __restrict__ trust,
    const float* __restrict__ b2g,
    const float* __restrict__ pack,
    float* __restrict__ out) {
  const int b = blockIdx.x;
  const int tid = threadIdx.x;
  const int wave = tid >> 6;
  const int lane = tid & 63;

  __shared__ float ssort[NNEI * 12];  // sorted slots: {s0..s5, tw} stride 12 (48B, float4-aligned)
  __shared__ int scnt[4][3];          // per-wave per-role counts

  // ---- phase 1: coalesced global loads, per-role ballots ----
  const size_t rowb = (size_t)b * NNEI;
  const int myrole = roles[rowb + tid];
  const int mymask = maskp[rowb + tid];
  const float mytw = trust[rowb + tid];
  const float* sp = states + rowb * NDIM + (size_t)tid * NDIM;
  const float2 sA = *(const float2*)(sp);
  const float2 sB = *(const float2*)(sp + 2);
  const float2 sC = *(const float2*)(sp + 4);
  const bool active = (mymask != 0);

  unsigned long long bal0 = __ballot(active && (myrole == 0));
  unsigned long long bal1 = __ballot(active && (myrole == 1));
  unsigned long long bal2 = __ballot(active && (myrole == 2));
  if (lane < 3) {
    unsigned long long bb = (lane == 0) ? bal0 : (lane == 1) ? bal1 : bal2;
    scnt[wave][lane] = __popcll(bb);
  }
  __syncthreads();

  // ---- phase 2: compute sorted position, write record ----
  int cw[4][3];
#pragma unroll
  for (int w = 0; w < 4; ++w)
#pragma unroll
    for (int r = 0; r < 3; ++r) cw[w][r] = scnt[w][r];
  const int tot0 = cw[0][0] + cw[1][0] + cw[2][0] + cw[3][0];
  const int tot1 = cw[0][1] + cw[1][1] + cw[2][1] + cw[3][1];
  const int tot2 = cw[0][2] + cw[1][2] + cw[2][2] + cw[3][2];
  int basev[3];
  basev[0] = 0; basev[1] = tot0; basev[2] = tot0 + tot1;
  int totv[3] = {tot0, tot1, tot2};

  if (active) {
    unsigned long long mybal = (myrole == 0) ? bal0 : (myrole == 1) ? bal1 : bal2;
    unsigned long long lt = (1ull << lane) - 1ull;
    int rank = __popcll(mybal & lt);
    int wbase = 0;
#pragma unroll
    for (int w = 0; w < 4; ++w)
      if (w < wave) wbase += cw[w][myrole];
    int pos = basev[myrole] + wbase + rank;  // < 256 by construction
    float* dst = ssort + pos * 12;
    *(float4*)dst = make_float4(sA.x, sA.y, sB.x, sB.y);
    *(float2*)(dst + 4) = make_float2(sC.x, sC.y);
    dst[6] = mytw;
  }
  __syncthreads();

  // ---- phase 3: wave r computes role r's scores, softmax, weighted sum ----
  if (wave < 3) {
    const int r = wave;
    const int cnt = __builtin_amdgcn_readfirstlane(totv[r]);
    const int base = __builtin_amdgcn_readfirstlane(basev[r]);
    const float* wp = pack + (size_t)(__builtin_amdgcn_readfirstlane(r)) * (NHID * 8);
    const float b2v = b2g[r];
    // Reference max includes the 0 entries from non-matching/masked slots
    // (present whenever cnt < 256).
    float mx = (cnt < NNEI) ? 0.f : -INFINITY;
    float sck[4] = {0.f, 0.f, 0.f, 0.f};
#pragma unroll
    for (int k = 0; k < 4; ++k) {
      if (k * 64 >= cnt) break;  // wave-uniform
      const int idx = k * 64 + lane;
      const bool act = idx < cnt;
      int p = base + idx; p = (p > NNEI - 1) ? (NNEI - 1) : p;
      const float* s = ssort + p * 12;
      const float4 v4 = *(const float4*)s;
      const float2 v2 = *(const float2*)(s + 4);
      float sc = b2v;
#pragma unroll
      for (int h = 0; h < NHID; ++h) {
        const float* w = wp + h * 8;  // uniform address -> scalar loads
        float a = w[6];
        a = fmaf(v4.x, w[0], a);
        a = fmaf(v4.y, w[1], a);
        a = fmaf(v4.z, w[2], a);
        a = fmaf(v4.w, w[3], a);
        a = fmaf(v2.x, w[4], a);
        a = fmaf(v2.y, w[5], a);
        a = fmaxf(a, 0.f);
        sc = fmaf(a, w[7], sc);
      }
      sck[k] = sc;
      mx = act ? fmaxf(mx, sc) : mx;
    }
#pragma unroll
    for (int off = 32; off >= 1; off >>= 1)
      mx = fmaxf(mx, __shfl_xor(mx, off));

    float Se = 0.f, Set = 0.f;
    float Sd0 = 0.f, Sd1 = 0.f, Sd2 = 0.f, Sd3 = 0.f, Sd4 = 0.f, Sd5 = 0.f;
#pragma unroll
    for (int k = 0; k < 4; ++k) {
      if (k * 64 >= cnt) break;
      const int idx = k * 64 + lane;
      const bool act = idx < cnt;
      int p = base + idx; p = (p > NNEI - 1) ? (NNEI - 1) : p;
      const float* s = ssort + p * 12;
      float4 v4 = *(const float4*)s;
      float2 v2 = *(const float2*)(s + 4);
      float tw = s[6];
      if (!act) {  // select-gate: never multiply potential garbage by 0
        v4 = make_float4(0.f, 0.f, 0.f, 0.f);
        v2 = make_float2(0.f, 0.f);
        tw = 0.f;
      }
      const float e = act ? __expf(sck[k] - mx) : 0.f;
      const float et = e * tw;
      Se += e; Set += et;
      Sd0 = fmaf(et, v4.x, Sd0);
      Sd1 = fmaf(et, v4.y, Sd1);
      Sd2 = fmaf(et, v4.z, Sd2);
      Sd3 = fmaf(et, v4.w, Sd3);
      Sd4 = fmaf(et, v2.x, Sd4);
      Sd5 = fmaf(et, v2.y, Sd5);
    }
    // full butterfly reduction for all 8 quantities (pure shuffles, no LDS)
    float q[8] = {Se, Set, Sd0, Sd1, Sd2, Sd3, Sd4, Sd5};
#pragma unroll
    for (int i = 0; i < 8; ++i) {
#pragma unroll
      for (int off = 1; off < 64; off <<= 1)
        q[i] += __shfl_xor(q[i], off);
    }
    const float denom = q[0] + 1e-8f;
    const float ws = fmaxf(q[1] / denom, 1e-8f);
    float num = q[2];
    num = (lane == 1) ? q[3] : num;
    num = (lane == 2) ? q[4] : num;
    num = (lane == 3) ? q[5] : num;
    num = (lane == 4) ? q[6] : num;
    num = (lane == 5) ? q[7] : num;
    if (lane < NDIM) {
      out[(size_t)b * (NROLE * NDIM) + r * NDIM + lane] = (num / denom) / ws;
    }
  }
}

extern "C" void kernel_launch(void* const* d_in, const int* in_sizes, int n_in,
                              void* d_out, int out_size, void* d_ws, size_t ws_size,
                              hipStream_t stream) {
  const float* states = (const float*)d_in[0];
  const int* roles = (const int*)d_in[1];
  const int* maskp = (const int*)d_in[2];
  const float* trust = (const float*)d_in[3];
  const float* W1 = (const float*)d_in[4];
  const float* b1 = (const float*)d_in[5];
  const float* W2 = (const float*)d_in[6];
  const float* b2 = (const float*)d_in[7];
  float* out = (float*)d_out;
  float* pack = (float*)d_ws;

  hmf_prep<<<1, 96, 0, stream>>>(W1, b1, W2, pack);
  hmf_main<<<NBATCH, 256, 0, stream>>>(states, roles, maskp, trust, b2, pack, out);
}

// Round 3
// 125.120 us; speedup vs baseline: 1.0528x; 1.0528x over previous
//
#include <hip/hip_runtime.h>
#include <math.h>

#define NBATCH 8192
#define NNEI 256
#define NROLE 3
#define NHID 32
#define NDIM 6

// Pre-pack weights: pack[(r*32+h)*8 + {0..5,6,7}] = {W1[r][0..5][h], b1[r][h], W2[r][h]}
__global__ void hmf_prep(const float* __restrict__ W1,
                         const float* __restrict__ b1,
                         const float* __restrict__ W2,
                         float* __restrict__ pack) {
  int j = threadIdx.x;
  if (j < NROLE * NHID) {
    int r = j >> 5;
    int h = j & 31;
#pragma unroll
    for (int d = 0; d < NDIM; ++d)
      pack[j * 8 + d] = W1[(r * NDIM + d) * NHID + h];
    pack[j * 8 + 6] = b1[r * NHID + h];
    pack[j * 8 + 7] = W2[r * NHID + h];
  }
}

__global__ __launch_bounds__(256) void hmf_main(
    const float* __restrict__ states,
    const int* __restrict__ roles,
    const int* __restrict__ maskp,   // bool arrives as int32
    const float* __restrict__ trust,
    const float* __restrict__ b2g,
    const float* __restrict__ pack,
    float* __restrict__ out) {
  const int b = blockIdx.x;
  const int tid = threadIdx.x;
  const int wave = tid >> 6;
  const int lane = tid & 63;

  __shared__ float ssort[NNEI * 12];  // sorted slots: {s0..s5, tw} stride 12 (48B, float4-aligned)
  __shared__ int scnt[4][3];          // per-wave per-role counts

  // ---- phase 1: coalesced global loads, per-role ballots ----
  const size_t rowb = (size_t)b * NNEI;
  const int myrole = roles[rowb + tid];
  const int mymask = maskp[rowb + tid];
  const float mytw = trust[rowb + tid];
  const float* sp = states + rowb * NDIM + (size_t)tid * NDIM;
  const float2 sA = *(const float2*)(sp);
  const float2 sB = *(const float2*)(sp + 2);
  const float2 sC = *(const float2*)(sp + 4);
  const bool active = (mymask != 0);

  unsigned long long bal0 = __ballot(active && (myrole == 0));
  unsigned long long bal1 = __ballot(active && (myrole == 1));
  unsigned long long bal2 = __ballot(active && (myrole == 2));
  if (lane < 3) {
    unsigned long long bb = (lane == 0) ? bal0 : (lane == 1) ? bal1 : bal2;
    scnt[wave][lane] = __popcll(bb);
  }
  __syncthreads();

  // ---- phase 2: compute sorted position, write record ----
  int cw[4][3];
#pragma unroll
  for (int w = 0; w < 4; ++w)
#pragma unroll
    for (int r = 0; r < 3; ++r) cw[w][r] = scnt[w][r];
  const int tot0 = cw[0][0] + cw[1][0] + cw[2][0] + cw[3][0];
  const int tot1 = cw[0][1] + cw[1][1] + cw[2][1] + cw[3][1];
  const int tot2 = cw[0][2] + cw[1][2] + cw[2][2] + cw[3][2];
  int basev[3];
  basev[0] = 0; basev[1] = tot0; basev[2] = tot0 + tot1;
  int totv[3] = {tot0, tot1, tot2};

  if (active) {
    unsigned long long mybal = (myrole == 0) ? bal0 : (myrole == 1) ? bal1 : bal2;
    unsigned long long lt = (1ull << lane) - 1ull;
    int rank = __popcll(mybal & lt);
    int wbase = 0;
#pragma unroll
    for (int w = 0; w < 4; ++w)
      if (w < wave) wbase += cw[w][myrole];
    int pos = basev[myrole] + wbase + rank;  // < 256 by construction
    float* dst = ssort + pos * 12;
    *(float4*)dst = make_float4(sA.x, sA.y, sB.x, sB.y);
    *(float2*)(dst + 4) = make_float2(sC.x, sC.y);
    dst[6] = mytw;
  }
  __syncthreads();

  // ---- phase 3: wave r computes role r's scores, softmax, weighted sum ----
  if (wave < 3) {
    const int r = wave;
    const int cnt = __builtin_amdgcn_readfirstlane(totv[r]);
    const int base = __builtin_amdgcn_readfirstlane(basev[r]);
    const float* wp = pack + (size_t)(__builtin_amdgcn_readfirstlane(r)) * (NHID * 8);
    const float b2v = b2g[r];
    // Reference max includes the 0 entries from non-matching/masked slots
    // (present whenever cnt < 256).
    float mx = (cnt < NNEI) ? 0.f : -INFINITY;

    // Retained per-k state (single LDS pass)
    float sck[4];
    float4 v4k[4];
    float2 v2k[4];
    float twk[4];
#pragma unroll
    for (int k = 0; k < 4; ++k) {
      sck[k] = 0.f;
      v4k[k] = make_float4(0.f, 0.f, 0.f, 0.f);
      v2k[k] = make_float2(0.f, 0.f);
      twk[k] = 0.f;
      if (k * 64 < cnt) {  // wave-uniform
        const int idx = k * 64 + lane;
        const bool act = idx < cnt;
        int p = base + idx;
        p = (p > NNEI - 1) ? (NNEI - 1) : p;
        const float* s = ssort + p * 12;
        float4 v4 = *(const float4*)s;
        float2 v2 = *(const float2*)(s + 4);
        float tw = s[6];
        if (!act) {  // select-gate: never rely on garbage
          v4 = make_float4(0.f, 0.f, 0.f, 0.f);
          v2 = make_float2(0.f, 0.f);
          tw = 0.f;
        }
        // MLP: 4 independent accumulators to break the serial fma chain
        float ac0 = 0.f, ac1 = 0.f, ac2 = 0.f, ac3 = 0.f;
#pragma unroll
        for (int h = 0; h < NHID; h += 4) {
          const float* w0 = wp + (h + 0) * 8;
          const float* w1 = wp + (h + 1) * 8;
          const float* w2 = wp + (h + 2) * 8;
          const float* w3 = wp + (h + 3) * 8;
          float a0 = w0[6], a1 = w1[6], a2 = w2[6], a3 = w3[6];
          a0 = fmaf(v4.x, w0[0], a0); a1 = fmaf(v4.x, w1[0], a1);
          a2 = fmaf(v4.x, w2[0], a2); a3 = fmaf(v4.x, w3[0], a3);
          a0 = fmaf(v4.y, w0[1], a0); a1 = fmaf(v4.y, w1[1], a1);
          a2 = fmaf(v4.y, w2[1], a2); a3 = fmaf(v4.y, w3[1], a3);
          a0 = fmaf(v4.z, w0[2], a0); a1 = fmaf(v4.z, w1[2], a1);
          a2 = fmaf(v4.z, w2[2], a2); a3 = fmaf(v4.z, w3[2], a3);
          a0 = fmaf(v4.w, w0[3], a0); a1 = fmaf(v4.w, w1[3], a1);
          a2 = fmaf(v4.w, w2[3], a2); a3 = fmaf(v4.w, w3[3], a3);
          a0 = fmaf(v2.x, w0[4], a0); a1 = fmaf(v2.x, w1[4], a1);
          a2 = fmaf(v2.x, w2[4], a2); a3 = fmaf(v2.x, w3[4], a3);
          a0 = fmaf(v2.y, w0[5], a0); a1 = fmaf(v2.y, w1[5], a1);
          a2 = fmaf(v2.y, w2[5], a2); a3 = fmaf(v2.y, w3[5], a3);
          a0 = fmaxf(a0, 0.f); a1 = fmaxf(a1, 0.f);
          a2 = fmaxf(a2, 0.f); a3 = fmaxf(a3, 0.f);
          ac0 = fmaf(a0, w0[7], ac0); ac1 = fmaf(a1, w1[7], ac1);
          ac2 = fmaf(a2, w2[7], ac2); ac3 = fmaf(a3, w3[7], ac3);
        }
        const float sc = b2v + ((ac0 + ac1) + (ac2 + ac3));
        sck[k] = sc;
        v4k[k] = v4; v2k[k] = v2; twk[k] = tw;
        mx = act ? fmaxf(mx, sc) : mx;
      }
    }
#pragma unroll
    for (int off = 32; off >= 1; off >>= 1)
      mx = fmaxf(mx, __shfl_xor(mx, off));

    // second pass: pure VALU (state retained in registers)
    float Se = 0.f, Set = 0.f;
    float Sd0 = 0.f, Sd1 = 0.f, Sd2 = 0.f, Sd3 = 0.f, Sd4 = 0.f, Sd5 = 0.f;
#pragma unroll
    for (int k = 0; k < 4; ++k) {
      if (k * 64 < cnt) {
        const int idx = k * 64 + lane;
        const bool act = idx < cnt;
        const float e = act ? __expf(sck[k] - mx) : 0.f;
        const float et = e * twk[k];
        Se += e; Set += et;
        Sd0 = fmaf(et, v4k[k].x, Sd0);
        Sd1 = fmaf(et, v4k[k].y, Sd1);
        Sd2 = fmaf(et, v4k[k].z, Sd2);
        Sd3 = fmaf(et, v4k[k].w, Sd3);
        Sd4 = fmaf(et, v2k[k].x, Sd4);
        Sd5 = fmaf(et, v2k[k].y, Sd5);
      }
    }
    // full butterfly reduction for all 8 quantities (pure shuffles, no LDS)
    float q[8] = {Se, Set, Sd0, Sd1, Sd2, Sd3, Sd4, Sd5};
#pragma unroll
    for (int i = 0; i < 8; ++i) {
#pragma unroll
      for (int off = 1; off < 64; off <<= 1)
        q[i] += __shfl_xor(q[i], off);
    }
    const float denom = q[0] + 1e-8f;
    const float ws = fmaxf(q[1] / denom, 1e-8f);
    float num = q[2];
    num = (lane == 1) ? q[3] : num;
    num = (lane == 2) ? q[4] : num;
    num = (lane == 3) ? q[5] : num;
    num = (lane == 4) ? q[6] : num;
    num = (lane == 5) ? q[7] : num;
    if (lane < NDIM) {
      out[(size_t)b * (NROLE * NDIM) + r * NDIM + lane] = (num / denom) / ws;
    }
  }
}

extern "C" void kernel_launch(void* const* d_in, const int* in_sizes, int n_in,
                              void* d_out, int out_size, void* d_ws, size_t ws_size,
                              hipStream_t stream) {
  const float* states = (const float*)d_in[0];
  const int* roles = (const int*)d_in[1];
  const int* maskp = (const int*)d_in[2];
  const float* trust = (const float*)d_in[3];
  const float* W1 = (const float*)d_in[4];
  const float* b1 = (const float*)d_in[5];
  const float* W2 = (const float*)d_in[6];
  const float* b2 = (const float*)d_in[7];
  float* out = (float*)d_out;
  float* pack = (float*)d_ws;

  hmf_prep<<<1, 96, 0, stream>>>(W1, b1, W2, pack);
  hmf_main<<<NBATCH, 256, 0, stream>>>(states, roles, maskp, trust, b2, pack, out);
}